// Round 1
// baseline (56.919 us; speedup 1.0000x reference)
//
#include <hip/hip_runtime.h>
#include <cmath>

#define NCLS 6
#define GRP 256
#define DIM 256
#define DCHUNK 32
#define TSTR 33   // DCHUNK + 1 pad -> LDS bank = (row + d) % 32, 2-way = free

// One block per anchor (class c = blockIdx.x>>8, row i = blockIdx.x&255).
// Computes sum over j!=i of log_prob[i,j] for that anchor, writes to partial[a].
__global__ __launch_bounds__(256) void rnc_anchor_kernel(
    const float* __restrict__ feat,    // [1536,256]
    const float* __restrict__ green,   // [1536,3]
    const float* __restrict__ red,     // [1536,3]
    const float* __restrict__ trans,   // [1536,3]
    const int*   __restrict__ sym,     // [1536,4]
    float* __restrict__ partial)       // [1536]
{
    __shared__ float fi[DIM];
    __shared__ float tile[GRP * TSTR];
    __shared__ float Lrow[GRP];
    __shared__ float ev[GRP];
    __shared__ float rbuf[4];

    const int a    = blockIdx.x;   // global anchor index
    const int c    = a >> 8;       // class
    const int i    = a & 255;      // row within class
    const int base = c << 8;       // class row offset
    const int t    = threadIdx.x;  // this thread owns column k = t

    // anchor feature row -> LDS (coalesced)
    fi[t] = feat[(size_t)a * DIM + t];

    // ---- feature distance: dist[t] = ||f_i - f_{base+t}||, LDS-tiled ----
    float acc = 0.f;
    for (int d0 = 0; d0 < DIM; d0 += DCHUNK) {
        __syncthreads();  // protect tile from prior iteration's readers (and cover fi on iter 0... see below)
        // cooperative load of rows [0,256) x cols [d0,d0+32): 2048 float4, 8 per thread
        #pragma unroll
        for (int it = 0; it < 8; ++it) {
            int idx = it * 256 + t;
            int row = idx >> 3;          // 8 float4 per row
            int c4  = (idx & 7) * 4;
            float4 v = *reinterpret_cast<const float4*>(
                feat + (size_t)(base + row) * DIM + d0 + c4);
            float* dst = tile + row * TSTR + c4;
            dst[0] = v.x; dst[1] = v.y; dst[2] = v.z; dst[3] = v.w;
        }
        __syncthreads();
        #pragma unroll
        for (int d = 0; d < DCHUNK; ++d) {
            float diff = fi[d0 + d] - tile[t * TSTR + d];
            acc = fmaf(diff, diff, acc);
        }
    }
    float dk = sqrtf(acc + 1e-12f);

    // ---- row max of logits == -min(dist)/TEMP : block min-reduce ----
    float mn = dk;
    #pragma unroll
    for (int off = 32; off > 0; off >>= 1)
        mn = fminf(mn, __shfl_down(mn, off));   // wave64 shuffle
    if ((t & 63) == 0) rbuf[t >> 6] = mn;
    __syncthreads();
    float dmin = fminf(fminf(rbuf[0], rbuf[1]), fminf(rbuf[2], rbuf[3]));
    float mx = -dmin * 0.5f;            // TEMP = 2.0
    float lg = -dk * 0.5f - mx;         // max-subtracted logit for column t
    ev[t] = expf(lg);

    // ---- label distance L[i, t] per class rule ----
    {
        const int ka = base + t;
        float gi0 = green[3*a], gi1 = green[3*a+1], gi2 = green[3*a+2];
        float ti0 = trans[3*a], ti1 = trans[3*a+1], ti2 = trans[3*a+2];
        float l1g = fabsf(gi0 - green[3*ka]) + fabsf(gi1 - green[3*ka+1]) + fabsf(gi2 - green[3*ka+2]);
        float l1t = fabsf(ti0 - trans[3*ka]) + fabsf(ti1 - trans[3*ka+1]) + fabsf(ti2 - trans[3*ka+2]);
        float L;
        if (c < 2) {
            // symmetric classes: no red axis
            L = 0.8f * l1g + 0.2f * l1t;
        } else {
            float ri0 = red[3*a], ri1 = red[3*a+1], ri2 = red[3*a+2];
            float l1r = fabsf(ri0 - red[3*ka]) + fabsf(ri1 - red[3*ka+1]) + fabsf(ri2 - red[3*ka+2]);
            float rot;
            if (c < 5) {
                rot = 0.5f * (l1g + l1r);
            } else {
                // mug: red axis only when BOTH anchor and k are non-symmetric
                float nsi  = (sym[4*a]  == 0) ? 1.f : 0.f;
                float nsk  = (sym[4*ka] == 0) ? 1.f : 0.f;
                float both = nsi * nsk;
                rot = (l1g + both * l1r) / (1.f + both);
            }
            L = 0.8f * rot + 0.2f * l1t;
        }
        Lrow[t] = L;
    }
    __syncthreads();   // Lrow + ev visible to all

    // ---- denom[t] = sum_{k!=i, L[k] >= L[t]} ev[k]  (uniform-k LDS broadcast) ----
    float Lj = Lrow[t];
    float denom = 0.f;
    for (int k = 0; k < GRP; ++k) {
        float add = (Lrow[k] >= Lj && k != i) ? ev[k] : 0.f;
        denom += add;
    }
    float part = (t == i) ? 0.f : (lg - logf(denom));

    // ---- block sum-reduce of part -> partial[a] ----
    #pragma unroll
    for (int off = 32; off > 0; off >>= 1)
        part += __shfl_down(part, off);
    __syncthreads();   // rbuf reuse safe: all reads of rbuf[0..3] happened before Lrow sync
    if ((t & 63) == 0) rbuf[t >> 6] = part;
    __syncthreads();
    if (t == 0) partial[a] = rbuf[0] + rbuf[1] + rbuf[2] + rbuf[3];
}

// Deterministic final reduction: loss = -sum(partial) / (n*(n-1)) / NCLS
__global__ __launch_bounds__(256) void rnc_finalize_kernel(
    const float* __restrict__ partial, float* __restrict__ out)
{
    __shared__ float rbuf[4];
    int t = threadIdx.x;
    float acc = 0.f;
    for (int k = t; k < NCLS * GRP; k += 256) acc += partial[k];
    #pragma unroll
    for (int off = 32; off > 0; off >>= 1)
        acc += __shfl_down(acc, off);
    if ((t & 63) == 0) rbuf[t >> 6] = acc;
    __syncthreads();
    if (t == 0)
        out[0] = -(rbuf[0] + rbuf[1] + rbuf[2] + rbuf[3]) / (256.f * 255.f * 6.f);
}

extern "C" void kernel_launch(void* const* d_in, const int* in_sizes, int n_in,
                              void* d_out, int out_size, void* d_ws, size_t ws_size,
                              hipStream_t stream)
{
    const float* feat  = (const float*)d_in[0];
    // d_in[1] = labels: unused (classes are contiguous GROUP-sized slices)
    const float* green = (const float*)d_in[2];
    const float* red   = (const float*)d_in[3];
    const float* trans = (const float*)d_in[4];
    const int*   sym   = (const int*)d_in[5];

    float* partial = (float*)d_ws;          // 1536 floats
    float* out     = (float*)d_out;

    rnc_anchor_kernel<<<NCLS * GRP, 256, 0, stream>>>(feat, green, red, trans, sym, partial);
    rnc_finalize_kernel<<<1, 256, 0, stream>>>(partial, out);
}

// Round 2
// 55.680 us; speedup vs baseline: 1.0222x; 1.0222x over previous
//
#include <hip/hip_runtime.h>
#include <cmath>

#define NCLS 6
#define GRP 256
#define DIM 256

// One block per anchor. Thread t owns column k = t of this anchor's row.
// Feature rows are L2-resident (whole input = 1.5 MB), so each thread streams
// its own row from global (float4); the anchor row is broadcast from LDS.
__global__ __launch_bounds__(256, 8) void rnc_anchor_kernel(
    const float* __restrict__ feat,    // [1536,256]
    const float* __restrict__ green,   // [1536,3]
    const float* __restrict__ red,     // [1536,3]
    const float* __restrict__ trans,   // [1536,3]
    const int*   __restrict__ sym,     // [1536,4]
    float* __restrict__ partial)       // [1536]
{
    __shared__ float fi[DIM];                       // anchor feature row (1 KB)
    __shared__ __align__(16) float2 LE[GRP];        // (L[k], ev[k]) packed (2 KB)
    __shared__ float rbuf[4];

    const int a    = blockIdx.x;
    const int c    = a >> 8;
    const int i    = a & 255;
    const int base = c << 8;
    const int t    = threadIdx.x;

    fi[t] = feat[(size_t)a * DIM + t];

    // ---- label distance L[i,t] (tiny, L2-resident gathers) ----
    float Lt;
    {
        const int ka = base + t;
        float l1g = fabsf(green[3*a]   - green[3*ka])
                  + fabsf(green[3*a+1] - green[3*ka+1])
                  + fabsf(green[3*a+2] - green[3*ka+2]);
        float l1t = fabsf(trans[3*a]   - trans[3*ka])
                  + fabsf(trans[3*a+1] - trans[3*ka+1])
                  + fabsf(trans[3*a+2] - trans[3*ka+2]);
        if (c < 2) {
            Lt = 0.8f * l1g + 0.2f * l1t;           // symmetric classes
        } else {
            float l1r = fabsf(red[3*a]   - red[3*ka])
                      + fabsf(red[3*a+1] - red[3*ka+1])
                      + fabsf(red[3*a+2] - red[3*ka+2]);
            float rot;
            if (c < 5) {
                rot = 0.5f * (l1g + l1r);
            } else {
                // mug: red axis only when both anchor and k are non-symmetric
                float both = ((sym[4*a] == 0) && (sym[4*ka] == 0)) ? 1.f : 0.f;
                rot = (l1g + both * l1r) / (1.f + both);
            }
            Lt = 0.8f * rot + 0.2f * l1t;
        }
    }
    __syncthreads();   // fi visible

    // ---- dist[t] = ||f_anchor - f_{base+t}||  (register-resident row) ----
    const float4* frow = reinterpret_cast<const float4*>(feat + (size_t)(base + t) * DIM);
    const float4* fbrd = reinterpret_cast<const float4*>(fi);
    float a0 = 0.f, a1 = 0.f, a2 = 0.f, a3 = 0.f;   // 4 independent fma chains
    #pragma unroll 4
    for (int q0 = 0; q0 < 64; q0 += 4) {            // 64B per batch -> L1-friendly
        float4 r0 = frow[q0];
        float4 r1 = frow[q0 + 1];
        float4 r2 = frow[q0 + 2];
        float4 r3 = frow[q0 + 3];
        float4 b0 = fbrd[q0];
        float4 b1 = fbrd[q0 + 1];
        float4 b2 = fbrd[q0 + 2];
        float4 b3 = fbrd[q0 + 3];
        float d;
        d = b0.x - r0.x; a0 = fmaf(d, d, a0);
        d = b0.y - r0.y; a1 = fmaf(d, d, a1);
        d = b0.z - r0.z; a2 = fmaf(d, d, a2);
        d = b0.w - r0.w; a3 = fmaf(d, d, a3);
        d = b1.x - r1.x; a0 = fmaf(d, d, a0);
        d = b1.y - r1.y; a1 = fmaf(d, d, a1);
        d = b1.z - r1.z; a2 = fmaf(d, d, a2);
        d = b1.w - r1.w; a3 = fmaf(d, d, a3);
        d = b2.x - r2.x; a0 = fmaf(d, d, a0);
        d = b2.y - r2.y; a1 = fmaf(d, d, a1);
        d = b2.z - r2.z; a2 = fmaf(d, d, a2);
        d = b2.w - r2.w; a3 = fmaf(d, d, a3);
        d = b3.x - r3.x; a0 = fmaf(d, d, a0);
        d = b3.y - r3.y; a1 = fmaf(d, d, a1);
        d = b3.z - r3.z; a2 = fmaf(d, d, a2);
        d = b3.w - r3.w; a3 = fmaf(d, d, a3);
    }
    float dk = sqrtf(((a0 + a1) + (a2 + a3)) + 1e-12f);

    // ---- row min of dist -> max logit ----
    float mn = dk;
    #pragma unroll
    for (int off = 32; off > 0; off >>= 1)
        mn = fminf(mn, __shfl_down(mn, off));
    if ((t & 63) == 0) rbuf[t >> 6] = mn;
    __syncthreads();
    float dmin = fminf(fminf(rbuf[0], rbuf[1]), fminf(rbuf[2], rbuf[3]));
    float lg  = (dmin - dk) * 0.5f;      // logit - max  (TEMP = 2)
    float evt = expf(lg);
    LE[t] = make_float2(Lt, evt);
    __syncthreads();   // LE visible

    // ---- denom[t] = sum_{k: L[k] >= L[t]} ev[k]  (k==i never qualifies for t!=i,
    //      since L[i]=0 < L[t]; the t==i row is discarded anyway) ----
    const float4* LE4 = reinterpret_cast<const float4*>(LE);
    float d0 = 0.f, d1 = 0.f;
    #pragma unroll 4
    for (int q = 0; q < 128; ++q) {
        float4 v = LE4[q];               // (L[2q], ev[2q], L[2q+1], ev[2q+1]) broadcast
        d0 += (v.x >= Lt) ? v.y : 0.f;
        d1 += (v.z >= Lt) ? v.w : 0.f;
    }
    float part = (t == i) ? 0.f : (lg - logf(d0 + d1));

    // ---- block sum-reduce -> partial[a] ----
    #pragma unroll
    for (int off = 32; off > 0; off >>= 1)
        part += __shfl_down(part, off);
    __syncthreads();   // rbuf reuse safe
    if ((t & 63) == 0) rbuf[t >> 6] = part;
    __syncthreads();
    if (t == 0) partial[a] = rbuf[0] + rbuf[1] + rbuf[2] + rbuf[3];
}

// loss = -sum(partial) / (n*(n-1)) / NCLS   (deterministic single-block reduce)
__global__ __launch_bounds__(256) void rnc_finalize_kernel(
    const float* __restrict__ partial, float* __restrict__ out)
{
    __shared__ float rbuf[4];
    int t = threadIdx.x;
    float acc = 0.f;
    for (int k = t; k < NCLS * GRP; k += 256) acc += partial[k];
    #pragma unroll
    for (int off = 32; off > 0; off >>= 1)
        acc += __shfl_down(acc, off);
    if ((t & 63) == 0) rbuf[t >> 6] = acc;
    __syncthreads();
    if (t == 0)
        out[0] = -(rbuf[0] + rbuf[1] + rbuf[2] + rbuf[3]) / (256.f * 255.f * 6.f);
}

extern "C" void kernel_launch(void* const* d_in, const int* in_sizes, int n_in,
                              void* d_out, int out_size, void* d_ws, size_t ws_size,
                              hipStream_t stream)
{
    const float* feat  = (const float*)d_in[0];
    // d_in[1] = labels: unused (classes are contiguous GROUP-sized slices)
    const float* green = (const float*)d_in[2];
    const float* red   = (const float*)d_in[3];
    const float* trans = (const float*)d_in[4];
    const int*   sym   = (const int*)d_in[5];

    float* partial = (float*)d_ws;          // 1536 floats
    float* out     = (float*)d_out;

    rnc_anchor_kernel<<<NCLS * GRP, 256, 0, stream>>>(feat, green, red, trans, sym, partial);
    rnc_finalize_kernel<<<1, 256, 0, stream>>>(partial, out);
}

// Round 3
// 34.791 us; speedup vs baseline: 1.6360x; 1.6004x over previous
//
#include <hip/hip_runtime.h>
#include <cmath>

#define NCLS 6
#define GRP 256
#define DIM 256
#define TA 4          // anchors per block in the main kernel

// ---------------- K0: per-class feature transpose ----------------
// ft[(c*256 + d)*256 + k] = feat[(c*256 + k)*256 + d]
// Grid: 6 classes x 16 (4x4 tiles of 64x64), 256 threads.
__global__ __launch_bounds__(256) void transpose_kernel(
    const float* __restrict__ feat, float* __restrict__ ft)
{
    __shared__ float tile[64][65];
    const int b  = blockIdx.x;
    const int c  = b >> 4;
    const int tt = b & 15;
    const int r0 = (tt >> 2) << 6;   // row tile (k) origin
    const int c0 = (tt & 3) << 6;    // col tile (d) origin
    const int t  = threadIdx.x;

    #pragma unroll
    for (int q = 0; q < 4; ++q) {
        int idx  = q * 256 + t;
        int row  = idx >> 4;             // 16 float4 per 64-float row
        int col4 = (idx & 15) << 2;
        float4 v = *reinterpret_cast<const float4*>(
            feat + (size_t)(c * 256 + r0 + row) * DIM + c0 + col4);
        tile[row][col4 + 0] = v.x; tile[row][col4 + 1] = v.y;
        tile[row][col4 + 2] = v.z; tile[row][col4 + 3] = v.w;
    }
    __syncthreads();
    #pragma unroll
    for (int q = 0; q < 4; ++q) {
        int idx = q * 256 + t;
        int dd  = idx >> 4;
        int r4  = (idx & 15) << 2;
        float4 o = make_float4(tile[r4][dd], tile[r4 + 1][dd],
                               tile[r4 + 2][dd], tile[r4 + 3][dd]);
        *reinterpret_cast<float4*>(
            ft + (size_t)(c * 256 + c0 + dd) * GRP + r0 + r4) = o;
    }
}

// ---------------- K1: fused dist + softmax-denom, 4 anchors/block ----------------
// Grid: 6*64 = 384 blocks, 256 threads (4 waves). Wave w owns anchor a0+w.
__global__ __launch_bounds__(256) void rnc_main_kernel(
    const float* __restrict__ ft,      // transposed features [6*256][256]
    const float* __restrict__ green,   // [1536,3]
    const float* __restrict__ red,     // [1536,3]
    const float* __restrict__ trans,   // [1536,3]
    const int*   __restrict__ sym,     // [1536,4]
    float* __restrict__ partial)       // [1536]
{
    __shared__ __align__(16) float4 fi4[DIM];        // anchor features packed: fi4[d] = F[a0..a0+3][d]
    __shared__ float dist_lds[TA][GRP + 1];          // pad -> conflict-free
    __shared__ __align__(16) float2 LE[TA][258];     // (L, ev); 258 keeps rows 16B-aligned

    const int b    = blockIdx.x;
    const int c    = b >> 6;           // class
    const int a0   = (b & 63) << 2;    // first in-class anchor of this block
    const int base = c << 8;           // class base row (global)
    const int t    = threadIdx.x;

    // stage fi4 from the transposed layout: fi4[d] = ft[(c*256+d)*256 + a0 .. a0+3]
    fi4[t] = *reinterpret_cast<const float4*>(ft + (size_t)(c * 256 + t) * GRP + a0);
    __syncthreads();

    // ---- phase 1: dist from the 4 anchors to column t (coalesced b32 loads) ----
    const float* cp = ft + (size_t)(c * 256) * GRP + t;   // + d*256
    float ac0 = 0.f, ac1 = 0.f, ac2 = 0.f, ac3 = 0.f;
    #pragma unroll 8
    for (int d = 0; d < DIM; ++d) {
        float v  = cp[(size_t)d * GRP];
        float4 f = fi4[d];
        float x;
        x = f.x - v; ac0 = fmaf(x, x, ac0);
        x = f.y - v; ac1 = fmaf(x, x, ac1);
        x = f.z - v; ac2 = fmaf(x, x, ac2);
        x = f.w - v; ac3 = fmaf(x, x, ac3);
    }
    dist_lds[0][t] = sqrtf(ac0 + 1e-12f);
    dist_lds[1][t] = sqrtf(ac1 + 1e-12f);
    dist_lds[2][t] = sqrtf(ac2 + 1e-12f);
    dist_lds[3][t] = sqrtf(ac3 + 1e-12f);
    __syncthreads();

    // ---- phase 2: wave w owns anchor a0+w; lane l owns j in {l, l+64, l+128, l+192} ----
    const int w  = t >> 6;
    const int l  = t & 63;
    const int iw = a0 + w;             // in-class anchor index
    const int ag = base + iw;          // global anchor row

    float dj0 = dist_lds[w][l];
    float dj1 = dist_lds[w][l + 64];
    float dj2 = dist_lds[w][l + 128];
    float dj3 = dist_lds[w][l + 192];

    float m = fminf(fminf(dj0, dj1), fminf(dj2, dj3));
    #pragma unroll
    for (int off = 32; off > 0; off >>= 1)
        m = fminf(m, __shfl_xor(m, off));
    const float dmin = m;

    // label distances + ev for the 4 owned j's
    {
        const float gx = green[3 * ag], gy = green[3 * ag + 1], gz = green[3 * ag + 2];
        const float tx = trans[3 * ag], ty = trans[3 * ag + 1], tz = trans[3 * ag + 2];
        float rx = 0.f, ry = 0.f, rz = 0.f;
        int syma = 0;
        if (c >= 2) { rx = red[3 * ag]; ry = red[3 * ag + 1]; rz = red[3 * ag + 2]; }
        if (c == 5) { syma = sym[4 * ag]; }

        float djv[4] = {dj0, dj1, dj2, dj3};
        #pragma unroll
        for (int jj = 0; jj < 4; ++jj) {
            const int j  = l + (jj << 6);
            const int kg = base + j;
            float l1g = fabsf(gx - green[3 * kg]) + fabsf(gy - green[3 * kg + 1])
                      + fabsf(gz - green[3 * kg + 2]);
            float l1t = fabsf(tx - trans[3 * kg]) + fabsf(ty - trans[3 * kg + 1])
                      + fabsf(tz - trans[3 * kg + 2]);
            float L;
            if (c < 2) {
                L = 0.8f * l1g + 0.2f * l1t;
            } else {
                float l1r = fabsf(rx - red[3 * kg]) + fabsf(ry - red[3 * kg + 1])
                          + fabsf(rz - red[3 * kg + 2]);
                float rot;
                if (c < 5) {
                    rot = 0.5f * (l1g + l1r);
                } else {
                    float both = ((syma == 0) && (sym[4 * kg] == 0)) ? 1.f : 0.f;
                    rot = (l1g + both * l1r) / (1.f + both);
                }
                L = 0.8f * rot + 0.2f * l1t;
            }
            float ev = __expf((dmin - djv[jj]) * 0.5f);
            LE[w][j] = make_float2(L, ev);
        }
    }
    __syncthreads();

    // ---- denom scan: one uniform b128 pair serves 4 k's x 4 j's ----
    float L0, L1, L2, L3;
    L0 = LE[w][l].x; L1 = LE[w][l + 64].x; L2 = LE[w][l + 128].x; L3 = LE[w][l + 192].x;
    const float4* p4 = reinterpret_cast<const float4*>(&LE[w][0]);
    float dn0 = 0.f, dn1 = 0.f, dn2 = 0.f, dn3 = 0.f;
    #pragma unroll 4
    for (int q = 0; q < 64; ++q) {
        float4 u = p4[2 * q];        // (L[4q],   ev[4q],   L[4q+1], ev[4q+1])
        float4 v = p4[2 * q + 1];    // (L[4q+2], ev[4q+2], L[4q+3], ev[4q+3])
        dn0 += (u.x >= L0) ? u.y : 0.f;
        dn1 += (u.x >= L1) ? u.y : 0.f;
        dn2 += (u.x >= L2) ? u.y : 0.f;
        dn3 += (u.x >= L3) ? u.y : 0.f;
        dn0 += (u.z >= L0) ? u.w : 0.f;
        dn1 += (u.z >= L1) ? u.w : 0.f;
        dn2 += (u.z >= L2) ? u.w : 0.f;
        dn3 += (u.z >= L3) ? u.w : 0.f;
        dn0 += (v.x >= L0) ? v.y : 0.f;
        dn1 += (v.x >= L1) ? v.y : 0.f;
        dn2 += (v.x >= L2) ? v.y : 0.f;
        dn3 += (v.x >= L3) ? v.y : 0.f;
        dn0 += (v.z >= L0) ? v.w : 0.f;
        dn1 += (v.z >= L1) ? v.w : 0.f;
        dn2 += (v.z >= L2) ? v.w : 0.f;
        dn3 += (v.z >= L3) ? v.w : 0.f;
    }

    // ---- per-anchor log_prob sum ----
    float part = 0.f;
    if (l + 0   != iw) part += (dmin - dj0) * 0.5f - __logf(dn0);
    if (l + 64  != iw) part += (dmin - dj1) * 0.5f - __logf(dn1);
    if (l + 128 != iw) part += (dmin - dj2) * 0.5f - __logf(dn2);
    if (l + 192 != iw) part += (dmin - dj3) * 0.5f - __logf(dn3);
    #pragma unroll
    for (int off = 32; off > 0; off >>= 1)
        part += __shfl_xor(part, off);
    if (l == 0) partial[ag] = part;
}

// ---------------- K2: finalize ----------------
__global__ __launch_bounds__(256) void rnc_finalize_kernel(
    const float* __restrict__ partial, float* __restrict__ out)
{
    __shared__ float rbuf[4];
    int t = threadIdx.x;
    float acc = 0.f;
    for (int k = t; k < NCLS * GRP; k += 256) acc += partial[k];
    #pragma unroll
    for (int off = 32; off > 0; off >>= 1)
        acc += __shfl_down(acc, off);
    if ((t & 63) == 0) rbuf[t >> 6] = acc;
    __syncthreads();
    if (t == 0)
        out[0] = -(rbuf[0] + rbuf[1] + rbuf[2] + rbuf[3]) / (256.f * 255.f * 6.f);
}

extern "C" void kernel_launch(void* const* d_in, const int* in_sizes, int n_in,
                              void* d_out, int out_size, void* d_ws, size_t ws_size,
                              hipStream_t stream)
{
    const float* feat  = (const float*)d_in[0];
    // d_in[1] = labels: unused (classes are contiguous GROUP-sized slices)
    const float* green = (const float*)d_in[2];
    const float* red   = (const float*)d_in[3];
    const float* trans = (const float*)d_in[4];
    const int*   sym   = (const int*)d_in[5];

    float* wsf     = (float*)d_ws;
    float* partial = wsf;              // 1536 floats
    float* ft      = wsf + 2048;       // 6*256*256 floats = 1.5 MB (16B-aligned offset)
    float* out     = (float*)d_out;

    transpose_kernel<<<NCLS * 16, 256, 0, stream>>>(feat, ft);
    rnc_main_kernel<<<NCLS * (GRP / TA), 256, 0, stream>>>(ft, green, red, trans, sym, partial);
    rnc_finalize_kernel<<<1, 256, 0, stream>>>(partial, out);
}